// Round 17
// baseline (6109.426 us; speedup 1.0000x reference)
//
#include <hip/hip_runtime.h>
#include <math.h>

// Problem constants (match reference)
#define B_   1024
#define NC   100
#define NN   101          // N = NC + 1
#define E_   128
#define T_   202          // 2*N
#define SVP  132          // sV row stride (16B-aligned rows)
#define NEGV   -1.0e9
#define GAPTHR 1.0e-3f    // decision guard band (round-14 proven)
#define INVSQE 0.08838834764831845f
#define INVSQED 0.08838834764831845

__device__ __forceinline__ float rdlane(float v, int l) {
    return __int_as_float(__builtin_amdgcn_readlane(__float_as_int(v), l));
}
__device__ __forceinline__ float fast_tanh(float x) {
    float xc = fminf(fmaxf(x, -15.f), 15.f);
    float e  = __expf(2.f * xc);
    return (e - 1.f) / (e + 1.f);
}

// ---------------------------------------------------------------------------
// kernel 0: M = Wk2 @ Wout^T (128x128) into ws as fp64 (fallback) + fp32 (fast)
// ---------------------------------------------------------------------------
__global__ void k_weights(const float* __restrict__ Wk2,
                          const float* __restrict__ Wout,
                          double* __restrict__ M64,
                          float* __restrict__ M32) {
    int g = blockIdx.x;   // 0..127
    int e = threadIdx.x;  // 0..127
    const float* w2 = Wk2 + g * E_;
    const float* wo = Wout + e * E_;
    double acc = 0.0;
#pragma unroll 8
    for (int f = 0; f < E_; ++f) acc += (double)w2[f] * (double)wo[f];
    M64[g * E_ + e] = acc;
    M32[g * E_ + e] = (float)acc;
}

// ---------------------------------------------------------------------------
// Exact fp64 fallback step, NOINLINE: isolates its register pressure from the
// fast path so the fast kernel fits the 128-reg (512,4) cap without spilling
// (rounds 10/11: inlined fallback always forced rA/rK2 to scratch). Caller's
// live regs are saved around the CALL only (rare). fp64 scratch overlays sV;
// V is restaged before return. All threads enter (sTrig is block-uniform).
// ---------------------------------------------------------------------------
__device__ __attribute__((noinline)) void fb_step(
    const float* __restrict__ emb,        // [101][128]
    const float* __restrict__ gemb_b,     // [128]
    const float* __restrict__ Wk1,
    const float* __restrict__ Wv,
    const float* __restrict__ Wq_fixed,
    const float* __restrict__ Wq_step,
    const double* __restrict__ M64,
    float* sV,                            // LDS: scratch overlay + restage
    const float* sDem, const float* sCoord,
    float* sD, int* sPrev, int* sMaskDepot,
    unsigned long long* sVis0, unsigned long long* sVis1,
    double* sCost, double* sLL, float* sPosX, float* sPosY,
    int* sTrig, int tid)
{
    double* dUZ = (double*)sV;   // [128][8] u1 then z  (rows 0..33 of sV)
    double* dSc = dUZ + 1024;    // [8][101]
    double* dQ1 = dUZ + 1832;    // [128] q1, later xd[101]
    double* dGl = dUZ + 1960;    // [128]
    double* dVg = dUZ + 2088;    // [128]

    // F0: q1d (Qfix recomputed fp64 from global)
    if (tid < E_) {
        double qf = 0.0, ks = 0.0;
        const float* ep = emb + (size_t)(*sPrev) * E_;
#pragma clang loop unroll(disable)
        for (int g = 0; g < E_; ++g) {
            qf += (double)gemb_b[g] * (double)Wq_fixed[(size_t)g * E_ + tid];
            ks += (double)ep[g]     * (double)Wq_step[(size_t)g * E_ + tid];
        }
        dQ1[tid] = (qf + ks + (double)(*sD) * (double)Wq_step[128 * E_ + tid]) * 0.25;
    }
    __syncthreads();
    // F1: u1[g][h]
    for (int idx = tid; idx < 1024; idx += 512) {
        int g = idx >> 3, hh = idx & 7;
        double u = 0.0;
#pragma clang loop unroll(disable)
        for (int d = 0; d < 16; ++d)
            u += dQ1[hh * 16 + d] * (double)Wk1[(size_t)g * E_ + hh * 16 + d];
        dUZ[idx] = u;
    }
    __syncthreads();
    // F2: scores
    for (int idx = tid; idx < 1024; idx += 512) {
        int k = idx & 127, hh = idx >> 7;
        if (k < NN) {
            bool mk;
            if (k == 0) mk = (*sMaskDepot != 0);
            else {
                int c = k - 1;
                bool vis = (c < 64) ? ((*sVis0 >> c) & 1ull) : ((*sVis1 >> (c - 64)) & 1ull);
                mk = vis || (sDem[c] > *sD);
            }
            if (mk) dSc[hh * NN + k] = NEGV;
            else {
                const float* ek = emb + (size_t)k * E_;
                double s = 0.0;
#pragma clang loop unroll(disable)
                for (int g = 0; g < E_; ++g)
                    s += (double)ek[g] * dUZ[g * 8 + hh];
                dSc[hh * NN + k] = s;
            }
        }
    }
    __syncthreads();
    // F3: per-head softmax (wave hh), normalized weights in place
    {
        int hh = tid >> 6, ln = tid & 63;
        int kA = ln, kB = ln + 64;
        double v1 = dSc[hh * NN + kA];
        double v2 = (kB < NN) ? dSc[hh * NN + kB] : -1.0e300;
        double m = fmax(v1, v2);
#pragma unroll
        for (int off = 32; off > 0; off >>= 1)
            m = fmax(m, __shfl_xor(m, off));
        double e1 = exp(v1 - m);
        double e2 = (kB < NN) ? exp(v2 - m) : 0.0;
        double s = e1 + e2;
#pragma unroll
        for (int off = 32; off > 0; off >>= 1)
            s += __shfl_xor(s, off);
        double inv = 1.0 / s;
        dSc[hh * NN + kA] = e1 * inv;
        if (kB < NN) dSc[hh * NN + kB] = e2 * inv;
    }
    __syncthreads();
    // F4: z[g][h]
    for (int idx = tid; idx < 1024; idx += 512) {
        int g = idx >> 3, hh = idx & 7;
        double z = 0.0;
#pragma clang loop unroll(disable)
        for (int k = 0; k < NN; ++k)
            z += dSc[hh * NN + k] * (double)emb[(size_t)k * E_ + g];
        dUZ[idx] = z;
    }
    __syncthreads();
    // F5: glimpse
    if (tid < E_) {
        int hh = tid >> 4;
        double g2 = 0.0;
#pragma clang loop unroll(disable)
        for (int g = 0; g < E_; ++g)
            g2 += dUZ[g * 8 + hh] * (double)Wv[(size_t)g * E_ + tid];
        dGl[tid] = g2;
    }
    __syncthreads();
    // F6: vg = M64 @ glimpse
    if (tid < E_) {
        double v = 0.0;
#pragma clang loop unroll(disable)
        for (int e = 0; e < E_; ++e)
            v += dGl[e] * M64[(size_t)tid * E_ + e];
        dVg[tid] = v;
    }
    __syncthreads();
    // F7: xd[k]
    if (tid < NN) {
        const float* ek = emb + (size_t)tid * E_;
        double x = 0.0;
#pragma clang loop unroll(disable)
        for (int g = 0; g < E_; ++g)
            x += (double)ek[g] * dVg[g];
        dQ1[tid] = x * INVSQED;
    }
    __syncthreads();
    // F8: fp64 argmax + LSE + commit
    if (tid < 64) {
        int kA = tid, kB = tid + 64;
        double x1 = dQ1[kA];
        bool mk1;
        if (kA == 0) mk1 = (*sMaskDepot != 0);
        else {
            int c = kA - 1;
            bool vis = (c < 64) ? ((*sVis0 >> c) & 1ull) : ((*sVis1 >> (c - 64)) & 1ull);
            mk1 = vis || (sDem[c] > *sD);
        }
        double x2 = 0.0; bool mk2 = true;
        if (kB < NN) {
            x2 = dQ1[kB];
            int c = kB - 1;
            bool vis = (c < 64) ? ((*sVis0 >> c) & 1ull) : ((*sVis1 >> (c - 64)) & 1ull);
            mk2 = vis || (sDem[c] > *sD);
        }
        double a1 = mk1 ? -1.0e300 : x1;
        double a2 = (kB < NN && !mk2) ? x2 : -1.0e300;
        double mv; int mi;
        if (a1 >= a2) { mv = a1; mi = kA; } else { mv = a2; mi = kB; }
#pragma unroll
        for (int off = 32; off > 0; off >>= 1) {
            double ov = __shfl_xor(mv, off);
            int    oi = __shfl_xor(mi, off);
            if (ov > mv || (ov == mv && oi < mi)) { mv = ov; mi = oi; }
        }
        double lmax = 10.0 * tanh(mv);
        double l1 = mk1 ? NEGV : 10.0 * tanh(x1);
        double l2 = (kB < NN) ? (mk2 ? NEGV : 10.0 * tanh(x2)) : 0.0;
        double s = exp(l1 - lmax) + ((kB < NN) ? exp(l2 - lmax) : 0.0);
#pragma unroll
        for (int off = 32; off > 0; off >>= 1)
            s += __shfl_xor(s, off);
        if (tid == 0) {
            int nxt = mi;
            *sLL += -log(s);
            bool isdep = (nxt == 0);
            if (isdep) {
                *sD = 1.0f;
            } else {
                int c = nxt - 1;
                *sD = *sD - sDem[c];
                if (c < 64) *sVis0 |= (1ull << c);
                else        *sVis1 |= (1ull << (c - 64));
            }
            bool allv = (*sVis0 == 0xFFFFFFFFFFFFFFFFull) &&
                        (*sVis1 == 0x0000000FFFFFFFFFull);
            *sMaskDepot = (isdep && !allv) ? 1 : 0;
            *sPrev = nxt;
            float cx = sCoord[2 * nxt], cy = sCoord[2 * nxt + 1];
            double dx = (double)cx - (double)(*sPosX);
            double dy = (double)cy - (double)(*sPosY);
            *sCost += sqrt(dx * dx + dy * dy + 1e-10);
            *sPosX = cx; *sPosY = cy;
            *sTrig = 0;
        }
    }
    __syncthreads();

    // Restage V (overlay destroyed rows 0..33; restage all data rows)
    for (int idx = tid; idx < NN * 32; idx += 512) {
        int k  = idx >> 5;
        int e4 = (idx & 31) * 4;
        const float* er = emb + (size_t)k * E_;
        float4 aV = {0.f, 0.f, 0.f, 0.f};
#pragma clang loop unroll(disable)
        for (int g = 0; g < E_; ++g) {
            float eg = er[g];
            float4 wv = *(const float4*)(Wv + (size_t)g * E_ + e4);
            aV.x += eg * wv.x; aV.y += eg * wv.y;
            aV.z += eg * wv.z; aV.w += eg * wv.w;
        }
        *(float4*)(sV + (size_t)k * SVP + e4) = aV;
    }
}

// ---------------------------------------------------------------------------
// Fast decoder (gks variant). 1 block / batch element, 512 threads, TARGET:
// 2 blocks/CU. __launch_bounds__(512,4) caps regs at 128/wave; the fp64
// fallback is noinline so the fast path's ~110-reg live set fits the cap
// (rounds 10/11: inlined fallback forced arrays to scratch at this cap).
// LDS ~63 KB: sV (padded) + small fp32 scratch; Kstep rows live in gks.
// 3 barriers/step (fused BC). fp64 near-tie fallback via fb_step().
// ---------------------------------------------------------------------------
__global__ __launch_bounds__(512, 4)
void k_decode_g(const float* __restrict__ depot_xy,
                const float* __restrict__ customer_xy,
                const float* __restrict__ demand,
                const float* __restrict__ node_emb,
                const float* __restrict__ graph_emb,
                const float* __restrict__ Wk1,
                const float* __restrict__ Wv,
                const float* __restrict__ Wq_fixed,
                const float* __restrict__ Wq_step,
                const double* __restrict__ M64,
                const float* __restrict__ M32,
                float* __restrict__ gks,          // [B][101][128] Kstep
                float* __restrict__ out)          // [2*B]: cost then ll
{
    __shared__ __align__(16) float sV[104 * SVP]; // 54.9 KB, padded rows
    __shared__ float  sF[1472];                   // fSc/gl/fPx 5.9 KB
    __shared__ float  sQfix32[E_];
    __shared__ float  sWqD32[E_];
    __shared__ float  sCoord[2 * NN];
    __shared__ float  sDem[NC];
    __shared__ float  sD;
    __shared__ double sCost, sLL;
    __shared__ float  sPosX, sPosY;
    __shared__ int    sPrev, sMaskDepot, sTrig, sOvf;
    __shared__ unsigned long long sVis0, sVis1;

    float* fSc = sF;            // [8][104] exp-scores (pads 101..103)
    float* gl  = sF + 832;      // [128] normalized glimpse
    float* fPx = sF + 960;      // [4][128] logit partials

    const int b      = blockIdx.x;
    const int tid    = threadIdx.x;
    const int lane   = tid & 63;
    const int h      = __builtin_amdgcn_readfirstlane(tid >> 6);   // head 0..7
    const int k1     = lane + 64;
    const int k_lane = tid & 127;
    const int q2u    = __builtin_amdgcn_readfirstlane(tid >> 7);   // 0..3
    const int e0     = q2u * 32;

    const float* emb    = node_emb + (size_t)b * NN * E_;
    const float* gemb_b = graph_emb + (size_t)b * E_;

    // ---------------- prologue ----------------
    if (tid < E_) {
        double acc = 0.0;
        for (int g = 0; g < E_; ++g)
            acc += (double)gemb_b[g] * (double)Wq_fixed[g * E_ + tid];
        sQfix32[tid] = (float)acc;
        sWqD32[tid]  = Wq_step[128 * E_ + tid];
    }
    if (tid < 2 * NN) {
        int k = tid >> 1, xy = tid & 1;
        sCoord[tid] = (k == 0) ? depot_xy[(size_t)b * 2 + xy]
                               : customer_xy[((size_t)b * NC + (k - 1)) * 2 + xy];
    }
    if (tid < NC) sDem[tid] = demand[(size_t)b * NC + tid];
    if (tid == 0) {
        sD = 1.f; sPrev = 0; sVis0 = 0ull; sVis1 = 0ull;
        sMaskDepot = 1; sCost = 0.0; sLL = 0.0; sTrig = 0; sOvf = 0;
        sPosX = depot_xy[(size_t)b * 2 + 0];
        sPosY = depot_xy[(size_t)b * 2 + 1];
    }
    // zero pad rows 101..103 of sV
    for (int i = tid; i < 3 * SVP; i += 512) sV[101 * SVP + i] = 0.f;

    // V into LDS; Kstep into gks
    for (int idx = tid; idx < NN * 32; idx += 512) {
        int k  = idx >> 5;
        int e4 = (idx & 31) * 4;
        const float* er = emb + (size_t)k * E_;
        float4 aV = {0.f, 0.f, 0.f, 0.f};
        float4 aK = {0.f, 0.f, 0.f, 0.f};
        for (int g = 0; g < E_; ++g) {
            float eg = er[g];
            float4 wv = *(const float4*)(Wv      + (size_t)g * E_ + e4);
            float4 wq = *(const float4*)(Wq_step + (size_t)g * E_ + e4);
            aV.x += eg * wv.x; aV.y += eg * wv.y;
            aV.z += eg * wv.z; aV.w += eg * wv.w;
            aK.x += eg * wq.x; aK.y += eg * wq.y;
            aK.z += eg * wq.z; aK.w += eg * wq.w;
        }
        *(float4*)(sV + (size_t)k * SVP + e4) = aV;
        *(float4*)(gks + ((size_t)b * NN + k) * E_ + e4) = aK;
    }

    // Per-wave K1h fragment (head h, nodes k=lane and k=lane+64)
    float rA[32];
#pragma unroll
    for (int j = 0; j < 32; ++j) rA[j] = 0.f;
    {
        const float* er0 = emb + (size_t)lane * E_;
        const float* er1 = emb + (size_t)((k1 < NN) ? k1 : lane) * E_;
        const float  e1s = (k1 < NN) ? 1.f : 0.f;
        const float* w1b = Wk1 + h * 16;
        for (int g = 0; g < E_; ++g) {
            float a0 = er0[g];
            float a1 = er1[g] * e1s;
            const float* w1 = w1b + (size_t)g * E_;
#pragma unroll
            for (int d = 0; d < 16; ++d) {
                rA[d]      += a0 * w1[d];
                rA[16 + d] += a1 * w1[d];
            }
        }
    }

    // K2t chunk (32 cols) into registers
    float rK2[32];
#pragma unroll
    for (int j = 0; j < 32; ++j) rK2[j] = 0.f;
    if (k_lane < NN) {
        const float* er = emb + (size_t)k_lane * E_;
        for (int g = 0; g < E_; ++g) {
            float eg = er[g];
            const float* mm = M32 + (size_t)g * E_ + e0;
#pragma unroll
            for (int j = 0; j < 32; ++j) rK2[j] += eg * mm[j];
        }
    }
    __syncthreads();

    // ---------------- sequential decode loop ----------------
    for (int t = 0; t < T_; ++t) {
        // ---- BC (fused): scores -> exp -> intra-wave exchange -> glimpse ----
        {
            int prev = sPrev;
            float Dv = sD;
            int d_ = h * 16 + (lane & 15);
            float ksv = gks[((size_t)b * NN + prev) * E_ + d_];
            float q1v = (sQfix32[d_] + ksv + Dv * sWqD32[d_]) * 0.25f;

            unsigned long long v0 = sVis0, v1 = sVis1;
            bool mk0, mk1;
            if (lane == 0) mk0 = (sMaskDepot != 0);
            else {
                int c = lane - 1;
                mk0 = ((v0 >> c) & 1ull) || (sDem[c] > Dv);
            }
            if (k1 < NN) {
                int c = k1 - 1;
                bool vis = (c < 64) ? ((v0 >> c) & 1ull)
                                    : ((v1 >> (c - 64)) & 1ull);
                mk1 = vis || (sDem[c] > Dv);
            } else mk1 = true;

            float s0a = 0.f, s0b = 0.f, s1a = 0.f, s1b = 0.f;
#pragma unroll
            for (int d = 0; d < 8; ++d) {
                float qd = rdlane(q1v, d);
                s0a += rA[d] * qd;
                s1a += rA[16 + d] * qd;
            }
#pragma unroll
            for (int d = 8; d < 16; ++d) {
                float qd = rdlane(q1v, d);
                s0b += rA[d] * qd;
                s1b += rA[16 + d] * qd;
            }
            float s0 = s0a + s0b, s1 = s1a + s1b;
            bool ovf = (!mk0 && s0 > 80.f) || (!mk1 && s1 > 80.f);
            if (__any(ovf)) { if (lane == 0) sOvf = 1; }
            float w0 = mk0 ? 0.f : __expf(fminf(s0, 80.f));
            float w1 = mk1 ? 0.f : __expf(fminf(s1, 80.f));
            fSc[h * 104 + lane] = w0;
            if (k1 < 104) fSc[h * 104 + k1] = w1;

            __builtin_amdgcn_wave_barrier();  // pin write->read program order

            int cq4 = lane >> 4;
            const float* sc = fSc + h * 104 + cq4 * 26;
            const float* vv = sV + (size_t)(cq4 * 26) * SVP + d_;
            float p = 0.f, ssum = 0.f;
#pragma unroll
            for (int j = 0; j < 26; ++j) {
                float wgt = sc[j];              // pads (101..103) are 0
                p    += wgt * vv[(size_t)j * SVP];
                ssum += wgt;
            }
            p    += __shfl_xor(p, 16);
            ssum += __shfl_xor(ssum, 16);
            p    += __shfl_xor(p, 32);
            ssum += __shfl_xor(ssum, 32);
            if (lane < 16) gl[d_] = p * (1.0f / ssum);
        }
        __syncthreads();

        // ---- D: logits via readlane dot over normalized glimpse ----
        {
            int ee = e0 + (tid & 31);
            float glv = gl[ee];
            float xa = 0.f, xb = 0.f, xc = 0.f, xd = 0.f;
#pragma unroll
            for (int j = 0; j < 8; ++j)   xa += rK2[j] * rdlane(glv, j);
#pragma unroll
            for (int j = 8; j < 16; ++j)  xb += rK2[j] * rdlane(glv, j);
#pragma unroll
            for (int j = 16; j < 24; ++j) xc += rK2[j] * rdlane(glv, j);
#pragma unroll
            for (int j = 24; j < 32; ++j) xd += rK2[j] * rdlane(glv, j);
            if (k_lane < NN) fPx[q2u * E_ + k_lane] = (xa + xb) + (xc + xd);
        }
        __syncthreads();

        // ---- E: argmax + __any near-tie + commit ----
        if (tid < 64) {
            int kA = tid, kB = tid + 64;
            float xA = (fPx[kA] + fPx[128 + kA] + fPx[256 + kA] + fPx[384 + kA]) * INVSQE;
            bool mk1;
            if (kA == 0) mk1 = (sMaskDepot != 0);
            else {
                int c = kA - 1;
                bool vis = (c < 64) ? ((sVis0 >> c) & 1ull) : ((sVis1 >> (c - 64)) & 1ull);
                mk1 = vis || (sDem[c] > sD);
            }
            float xB = -3.0e38f; bool mk2 = true;
            if (kB < NN) {
                xB = (fPx[kB] + fPx[128 + kB] + fPx[256 + kB] + fPx[384 + kB]) * INVSQE;
                int c = kB - 1;
                bool vis = (c < 64) ? ((sVis0 >> c) & 1ull) : ((sVis1 >> (c - 64)) & 1ull);
                mk2 = vis || (sDem[c] > sD);
            }
            float a1v = mk1 ? -3.0e38f : xA;
            float a2v = mk2 ? -3.0e38f : xB;
            float m1; int mi;
            if (a2v > a1v) { m1 = a2v; mi = kB; }
            else           { m1 = a1v; mi = kA; }
            float ls = 0.f;
            if (!mk1)              ls += __expf(10.f * fast_tanh(xA));
            if (kB < NN && !mk2)   ls += __expf(10.f * fast_tanh(xB));
#pragma unroll
            for (int off = 32; off > 0; off >>= 1) {
                float om1 = __shfl_xor(m1, off);
                int   omi = __shfl_xor(mi, off);
                ls += __shfl_xor(ls, off);
                if (om1 > m1 || (om1 == m1 && omi < mi)) { m1 = om1; mi = omi; }
            }
            bool near = false;
            if (!mk1 && kA != mi && a1v > m1 - GAPTHR) near = true;
            if (!mk2 && kB != mi && a2v > m1 - GAPTHR) near = true;
            bool trigAny = __any(near);
            if (tid == 0) {
                bool trig = trigAny || (sOvf != 0) || !(m1 == m1);
                sOvf = 0;
                if (trig) {
                    sTrig = 1;
                } else {
                    float lsel = 10.f * fast_tanh(m1);
                    float logp = lsel - __logf(ls);
                    int nxt = mi;
                    sLL += (double)logp;
                    bool isdep = (nxt == 0);
                    if (isdep) {
                        sD = 1.0f;
                    } else {
                        int c = nxt - 1;
                        sD = sD - sDem[c];
                        if (c < 64) sVis0 |= (1ull << c);
                        else        sVis1 |= (1ull << (c - 64));
                    }
                    bool allv = (sVis0 == 0xFFFFFFFFFFFFFFFFull) &&
                                (sVis1 == 0x0000000FFFFFFFFFull);
                    sMaskDepot = (isdep && !allv) ? 1 : 0;
                    sPrev = nxt;
                    float cx = sCoord[2 * nxt], cy = sCoord[2 * nxt + 1];
                    double dx = (double)cx - (double)sPosX;
                    double dy = (double)cy - (double)sPosY;
                    sCost += sqrt(dx * dx + dy * dy + 1e-10);
                    sPosX = cx; sPosY = cy;
                }
            }
        }
        __syncthreads();

        // ---- Fallback (rare, noinline) ----
        if (sTrig) {
            fb_step(emb, gemb_b, Wk1, Wv, Wq_fixed, Wq_step, M64,
                    sV, sDem, sCoord, &sD, &sPrev, &sMaskDepot,
                    &sVis0, &sVis1, &sCost, &sLL, &sPosX, &sPosY,
                    &sTrig, tid);
            __syncthreads();   // restaged sV visible before next BC
        }
    }

    if (tid == 0) {
        double dx = (double)sCoord[0] - (double)sPosX;
        double dy = (double)sCoord[1] - (double)sPosY;
        out[b]      = (float)(sCost + sqrt(dx * dx + dy * dy + 1e-10));
        out[B_ + b] = (float)sLL;
    }
}

// ---------------------------------------------------------------------------
// Safety-net decoder (round-15/16 champion, sKs in LDS) for ws too small.
// ---------------------------------------------------------------------------
__global__ __launch_bounds__(512, 2)
void k_decode_l(const float* __restrict__ depot_xy,
                const float* __restrict__ customer_xy,
                const float* __restrict__ demand,
                const float* __restrict__ node_emb,
                const float* __restrict__ graph_emb,
                const float* __restrict__ Wk1,
                const float* __restrict__ Wv,
                const float* __restrict__ Wq_fixed,
                const float* __restrict__ Wq_step,
                const double* __restrict__ M64,
                const float* __restrict__ M32,
                float* __restrict__ out)
{
    __shared__ float  sKs[NN * E_];
    __shared__ __align__(16) float sV[104 * SVP];
    __shared__ float  sF[1472];
    __shared__ float  sQfix32[E_];
    __shared__ float  sWqD32[E_];
    __shared__ float  sCoord[2 * NN];
    __shared__ float  sDem[NC];
    __shared__ float  sD;
    __shared__ double sCost, sLL;
    __shared__ float  sPosX, sPosY;
    __shared__ int    sPrev, sMaskDepot, sTrig, sOvf;
    __shared__ unsigned long long sVis0, sVis1;

    float* fSc = sF;
    float* gl  = sF + 832;
    float* fPx = sF + 960;

    const int b      = blockIdx.x;
    const int tid    = threadIdx.x;
    const int lane   = tid & 63;
    const int h      = __builtin_amdgcn_readfirstlane(tid >> 6);
    const int k1     = lane + 64;
    const int k_lane = tid & 127;
    const int q2u    = __builtin_amdgcn_readfirstlane(tid >> 7);
    const int e0     = q2u * 32;

    const float* emb    = node_emb + (size_t)b * NN * E_;
    const float* gemb_b = graph_emb + (size_t)b * E_;

    if (tid < E_) {
        double acc = 0.0;
        for (int g = 0; g < E_; ++g)
            acc += (double)gemb_b[g] * (double)Wq_fixed[g * E_ + tid];
        sQfix32[tid] = (float)acc;
        sWqD32[tid]  = Wq_step[128 * E_ + tid];
    }
    if (tid < 2 * NN) {
        int k = tid >> 1, xy = tid & 1;
        sCoord[tid] = (k == 0) ? depot_xy[(size_t)b * 2 + xy]
                               : customer_xy[((size_t)b * NC + (k - 1)) * 2 + xy];
    }
    if (tid < NC) sDem[tid] = demand[(size_t)b * NC + tid];
    if (tid == 0) {
        sD = 1.f; sPrev = 0; sVis0 = 0ull; sVis1 = 0ull;
        sMaskDepot = 1; sCost = 0.0; sLL = 0.0; sTrig = 0; sOvf = 0;
        sPosX = depot_xy[(size_t)b * 2 + 0];
        sPosY = depot_xy[(size_t)b * 2 + 1];
    }
    for (int i = tid; i < 3 * SVP; i += 512) sV[101 * SVP + i] = 0.f;

    for (int idx = tid; idx < NN * 32; idx += 512) {
        int k  = idx >> 5;
        int e4 = (idx & 31) * 4;
        const float* er = emb + (size_t)k * E_;
        float4 aV = {0.f, 0.f, 0.f, 0.f};
        float4 aK = {0.f, 0.f, 0.f, 0.f};
        for (int g = 0; g < E_; ++g) {
            float eg = er[g];
            float4 wv = *(const float4*)(Wv      + (size_t)g * E_ + e4);
            float4 wq = *(const float4*)(Wq_step + (size_t)g * E_ + e4);
            aV.x += eg * wv.x; aV.y += eg * wv.y;
            aV.z += eg * wv.z; aV.w += eg * wv.w;
            aK.x += eg * wq.x; aK.y += eg * wq.y;
            aK.z += eg * wq.z; aK.w += eg * wq.w;
        }
        *(float4*)(sV  + (size_t)k * SVP + e4) = aV;
        *(float4*)(sKs + (size_t)k * E_  + e4) = aK;
    }

    float rA[32];
#pragma unroll
    for (int j = 0; j < 32; ++j) rA[j] = 0.f;
    {
        const float* er0 = emb + (size_t)lane * E_;
        const float* er1 = emb + (size_t)((k1 < NN) ? k1 : lane) * E_;
        const float  e1s = (k1 < NN) ? 1.f : 0.f;
        const float* w1b = Wk1 + h * 16;
        for (int g = 0; g < E_; ++g) {
            float a0 = er0[g];
            float a1 = er1[g] * e1s;
            const float* w1 = w1b + (size_t)g * E_;
#pragma unroll
            for (int d = 0; d < 16; ++d) {
                rA[d]      += a0 * w1[d];
                rA[16 + d] += a1 * w1[d];
            }
        }
    }

    float rK2[32];
#pragma unroll
    for (int j = 0; j < 32; ++j) rK2[j] = 0.f;
    if (k_lane < NN) {
        const float* er = emb + (size_t)k_lane * E_;
        for (int g = 0; g < E_; ++g) {
            float eg = er[g];
            const float* mm = M32 + (size_t)g * E_ + e0;
#pragma unroll
            for (int j = 0; j < 32; ++j) rK2[j] += eg * mm[j];
        }
    }
    __syncthreads();

    for (int t = 0; t < T_; ++t) {
        {
            int prev = sPrev;
            float Dv = sD;
            int d_ = h * 16 + (lane & 15);
            float q1v = (sQfix32[d_] + sKs[(size_t)prev * E_ + d_]
                         + Dv * sWqD32[d_]) * 0.25f;

            unsigned long long v0 = sVis0, v1 = sVis1;
            bool mk0, mk1;
            if (lane == 0) mk0 = (sMaskDepot != 0);
            else {
                int c = lane - 1;
                mk0 = ((v0 >> c) & 1ull) || (sDem[c] > Dv);
            }
            if (k1 < NN) {
                int c = k1 - 1;
                bool vis = (c < 64) ? ((v0 >> c) & 1ull)
                                    : ((v1 >> (c - 64)) & 1ull);
                mk1 = vis || (sDem[c] > Dv);
            } else mk1 = true;

            float s0a = 0.f, s0b = 0.f, s1a = 0.f, s1b = 0.f;
#pragma unroll
            for (int d = 0; d < 8; ++d) {
                float qd = rdlane(q1v, d);
                s0a += rA[d] * qd;
                s1a += rA[16 + d] * qd;
            }
#pragma unroll
            for (int d = 8; d < 16; ++d) {
                float qd = rdlane(q1v, d);
                s0b += rA[d] * qd;
                s1b += rA[16 + d] * qd;
            }
            float s0 = s0a + s0b, s1 = s1a + s1b;
            bool ovf = (!mk0 && s0 > 80.f) || (!mk1 && s1 > 80.f);
            if (__any(ovf)) { if (lane == 0) sOvf = 1; }
            float w0 = mk0 ? 0.f : __expf(fminf(s0, 80.f));
            float w1 = mk1 ? 0.f : __expf(fminf(s1, 80.f));
            fSc[h * 104 + lane] = w0;
            if (k1 < 104) fSc[h * 104 + k1] = w1;

            __builtin_amdgcn_wave_barrier();

            int cq4 = lane >> 4;
            const float* sc = fSc + h * 104 + cq4 * 26;
            const float* vv = sV + (size_t)(cq4 * 26) * SVP + d_;
            float p = 0.f, ssum = 0.f;
#pragma unroll
            for (int j = 0; j < 26; ++j) {
                float wgt = sc[j];
                p    += wgt * vv[(size_t)j * SVP];
                ssum += wgt;
            }
            p    += __shfl_xor(p, 16);
            ssum += __shfl_xor(ssum, 16);
            p    += __shfl_xor(p, 32);
            ssum += __shfl_xor(ssum, 32);
            if (lane < 16) gl[d_] = p * (1.0f / ssum);
        }
        __syncthreads();

        {
            int ee = e0 + (tid & 31);
            float glv = gl[ee];
            float xa = 0.f, xb = 0.f, xc = 0.f, xd = 0.f;
#pragma unroll
            for (int j = 0; j < 8; ++j)   xa += rK2[j] * rdlane(glv, j);
#pragma unroll
            for (int j = 8; j < 16; ++j)  xb += rK2[j] * rdlane(glv, j);
#pragma unroll
            for (int j = 16; j < 24; ++j) xc += rK2[j] * rdlane(glv, j);
#pragma unroll
            for (int j = 24; j < 32; ++j) xd += rK2[j] * rdlane(glv, j);
            if (k_lane < NN) fPx[q2u * E_ + k_lane] = (xa + xb) + (xc + xd);
        }
        __syncthreads();

        if (tid < 64) {
            int kA = tid, kB = tid + 64;
            float xA = (fPx[kA] + fPx[128 + kA] + fPx[256 + kA] + fPx[384 + kA]) * INVSQE;
            bool mk1;
            if (kA == 0) mk1 = (sMaskDepot != 0);
            else {
                int c = kA - 1;
                bool vis = (c < 64) ? ((sVis0 >> c) & 1ull) : ((sVis1 >> (c - 64)) & 1ull);
                mk1 = vis || (sDem[c] > sD);
            }
            float xB = -3.0e38f; bool mk2 = true;
            if (kB < NN) {
                xB = (fPx[kB] + fPx[128 + kB] + fPx[256 + kB] + fPx[384 + kB]) * INVSQE;
                int c = kB - 1;
                bool vis = (c < 64) ? ((sVis0 >> c) & 1ull) : ((sVis1 >> (c - 64)) & 1ull);
                mk2 = vis || (sDem[c] > sD);
            }
            float a1v = mk1 ? -3.0e38f : xA;
            float a2v = mk2 ? -3.0e38f : xB;
            float m1; int mi;
            if (a2v > a1v) { m1 = a2v; mi = kB; }
            else           { m1 = a1v; mi = kA; }
            float ls = 0.f;
            if (!mk1)              ls += __expf(10.f * fast_tanh(xA));
            if (kB < NN && !mk2)   ls += __expf(10.f * fast_tanh(xB));
#pragma unroll
            for (int off = 32; off > 0; off >>= 1) {
                float om1 = __shfl_xor(m1, off);
                int   omi = __shfl_xor(mi, off);
                ls += __shfl_xor(ls, off);
                if (om1 > m1 || (om1 == m1 && omi < mi)) { m1 = om1; mi = omi; }
            }
            bool near = false;
            if (!mk1 && kA != mi && a1v > m1 - GAPTHR) near = true;
            if (!mk2 && kB != mi && a2v > m1 - GAPTHR) near = true;
            bool trigAny = __any(near);
            if (tid == 0) {
                bool trig = trigAny || (sOvf != 0) || !(m1 == m1);
                sOvf = 0;
                if (trig) {
                    sTrig = 1;
                } else {
                    float lsel = 10.f * fast_tanh(m1);
                    float logp = lsel - __logf(ls);
                    int nxt = mi;
                    sLL += (double)logp;
                    bool isdep = (nxt == 0);
                    if (isdep) {
                        sD = 1.0f;
                    } else {
                        int c = nxt - 1;
                        sD = sD - sDem[c];
                        if (c < 64) sVis0 |= (1ull << c);
                        else        sVis1 |= (1ull << (c - 64));
                    }
                    bool allv = (sVis0 == 0xFFFFFFFFFFFFFFFFull) &&
                                (sVis1 == 0x0000000FFFFFFFFFull);
                    sMaskDepot = (isdep && !allv) ? 1 : 0;
                    sPrev = nxt;
                    float cx = sCoord[2 * nxt], cy = sCoord[2 * nxt + 1];
                    double dx = (double)cx - (double)sPosX;
                    double dy = (double)cy - (double)sPosY;
                    sCost += sqrt(dx * dx + dy * dy + 1e-10);
                    sPosX = cx; sPosY = cy;
                }
            }
        }
        __syncthreads();

        if (sTrig) {
            fb_step(emb, gemb_b, Wk1, Wv, Wq_fixed, Wq_step, M64,
                    sV, sDem, sCoord, &sD, &sPrev, &sMaskDepot,
                    &sVis0, &sVis1, &sCost, &sLL, &sPosX, &sPosY,
                    &sTrig, tid);
            __syncthreads();
        }
    }

    if (tid == 0) {
        double dx = (double)sCoord[0] - (double)sPosX;
        double dy = (double)sCoord[1] - (double)sPosY;
        out[b]      = (float)(sCost + sqrt(dx * dx + dy * dy + 1e-10));
        out[B_ + b] = (float)sLL;
    }
}

// ---------------------------------------------------------------------------
extern "C" void kernel_launch(void* const* d_in, const int* in_sizes, int n_in,
                              void* d_out, int out_size, void* d_ws, size_t ws_size,
                              hipStream_t stream) {
    const float* depot = (const float*)d_in[0];
    const float* cust  = (const float*)d_in[1];
    const float* dem   = (const float*)d_in[2];
    const float* nemb  = (const float*)d_in[3];
    const float* gemb  = (const float*)d_in[4];
    const float* Wk1   = (const float*)d_in[5];
    const float* Wv    = (const float*)d_in[6];
    const float* Wk2   = (const float*)d_in[7];
    const float* Wqf   = (const float*)d_in[8];
    const float* Wout  = (const float*)d_in[9];
    const float* Wqs   = (const float*)d_in[10];
    float*  out = (float*)d_out;

    double* M64 = (double*)d_ws;                       // 128 KB @ 0
    float*  M32 = (float*)((char*)d_ws + 131072);      // 64 KB  @ 128K

    // Kstep workspace: [B][101][128] fp32 = 52.95 MB (proven, rounds 8-13)
    const size_t gks_off   = 196608;
    const size_t gks_bytes = (size_t)B_ * NN * E_ * sizeof(float);
    float* gks = (ws_size >= gks_off + gks_bytes)
               ? (float*)((char*)d_ws + gks_off) : nullptr;

    k_weights<<<dim3(128), dim3(128), 0, stream>>>(Wk2, Wout, M64, M32);
    if (gks) {
        k_decode_g<<<dim3(B_), dim3(512), 0, stream>>>(depot, cust, dem, nemb,
                                                       gemb, Wk1, Wv, Wqf, Wqs,
                                                       M64, M32, gks, out);
    } else {
        k_decode_l<<<dim3(B_), dim3(512), 0, stream>>>(depot, cust, dem, nemb,
                                                       gemb, Wk1, Wv, Wqf, Wqs,
                                                       M64, M32, out);
    }
}

// Round 18
// 3129.642 us; speedup vs baseline: 1.9521x; 1.9521x over previous
//
#include <hip/hip_runtime.h>
#include <math.h>

// Problem constants (match reference)
#define B_   1024
#define NC   100
#define NN   101          // N = NC + 1
#define E_   128
#define T_   202          // 2*N
#define SVP  132          // sV row stride (padded, 16B-aligned rows)
#define NEGV   -1.0e9
#define GAPTHR 1.0e-3f    // decision guard band (round-14 proven)
#define INVSQE 0.08838834764831845f
#define INVSQED 0.08838834764831845

__device__ __forceinline__ float rdlane(float v, int l) {
    return __int_as_float(__builtin_amdgcn_readlane(__float_as_int(v), l));
}
// fast tanh via native exp (decisions use pre-tanh values; LL err << 3.5)
__device__ __forceinline__ float fast_tanh(float x) {
    float xc = fminf(fmaxf(x, -15.f), 15.f);
    float e  = __expf(2.f * xc);
    return (e - 1.f) / (e + 1.f);
}

// ---------------------------------------------------------------------------
// kernel 0: M = Wk2 @ Wout^T (128x128) into ws as fp64 (fallback) + fp32 (fast)
// ---------------------------------------------------------------------------
__global__ void k_weights(const float* __restrict__ Wk2,
                          const float* __restrict__ Wout,
                          double* __restrict__ M64,
                          float* __restrict__ M32) {
    int g = blockIdx.x;   // 0..127
    int e = threadIdx.x;  // 0..127
    const float* w2 = Wk2 + g * E_;
    const float* wo = Wout + e * E_;
    double acc = 0.0;
#pragma unroll 8
    for (int f = 0; f < E_; ++f) acc += (double)w2[f] * (double)wo[f];
    M64[g * E_ + e] = acc;
    M32[g * E_ + e] = (float)acc;
}

// ---------------------------------------------------------------------------
// Main decoder. 1 block / batch element, 512 threads (8 waves), (512,2).
// Round-15 champion structure + BCD fusion: wave h computes scores -> exp ->
// glimpse dims [16h,16h+16) (in-register) -> per-head partial logits, all
// barrier-free (intra-wave LDS FIFO + wave_barrier). rK2 re-partitioned
// per-head (cols [16h,16h+16) x 2 nodes), loaded alongside rA (same col
// base). E sums 8 per-head partials. 2 barriers/step.
// Exact fp64 fallback on near-tie argmax (gap < GAPTHR), inline (proven).
// ---------------------------------------------------------------------------
__global__ __launch_bounds__(512, 2)
void k_decode(const float* __restrict__ depot_xy,
              const float* __restrict__ customer_xy,
              const float* __restrict__ demand,
              const float* __restrict__ node_emb,
              const float* __restrict__ graph_emb,
              const float* __restrict__ Wk1,
              const float* __restrict__ Wv,
              const float* __restrict__ Wq_fixed,
              const float* __restrict__ Wq_step,
              const double* __restrict__ M64,
              const float* __restrict__ M32,
              float* __restrict__ out)          // [2*B]: cost then ll
{
    __shared__ float  sKs[NN * E_];             // 51.7 KB Kstep rows fp32
    __shared__ __align__(16) float sV[104 * SVP]; // 54.9 KB V rows, padded
    __shared__ double sU[2224];                 // union scratch 17.8 KB
    __shared__ double sQfix64[E_];
    __shared__ double sWqD64[E_];
    __shared__ float  sQfix32[E_];
    __shared__ float  sWqD32[E_];
    __shared__ float  sCoord[2 * NN];
    __shared__ float  sDem[NC];
    __shared__ float  sD;
    __shared__ double sCost, sLL;
    __shared__ float  sPosX, sPosY;
    __shared__ int    sPrev, sMaskDepot, sTrig, sOvf;
    __shared__ unsigned long long sVis0, sVis1;

    // fast fp32 views (overlay the fp64 fallback scratch)
    float* fSc  = (float*)sU;           // [8][104] exp-scores (pads 101..103)
    float* fPx8 = (float*)sU + 832;     // [8][128] per-head logit partials
    // fallback fp64 views (not live at same time as fast views)
    double* dUZ = sU;                   // [128][8] u1 then z
    double* dSc = sU + 1024;            // [8][101] scores -> weights
    double* dQ1 = sU + 1832;            // [128] q1, later xd[101]
    double* dGl = sU + 1960;            // [128]
    double* dVg = sU + 2088;            // [128]

    const int b      = blockIdx.x;
    const int tid    = threadIdx.x;
    const int lane   = tid & 63;
    const int h      = __builtin_amdgcn_readfirstlane(tid >> 6);   // head 0..7
    const int k1     = lane + 64;                                  // 2nd node

    const float* emb = node_emb + (size_t)b * NN * E_;

    // ---------------- prologue ----------------
    if (tid < E_) {
        const float* ge = graph_emb + (size_t)b * E_;
        double acc = 0.0;
        for (int g = 0; g < E_; ++g)
            acc += (double)ge[g] * (double)Wq_fixed[g * E_ + tid];
        sQfix64[tid] = acc;
        sQfix32[tid] = (float)acc;
        sWqD64[tid]  = (double)Wq_step[128 * E_ + tid];
        sWqD32[tid]  = Wq_step[128 * E_ + tid];
    }
    if (tid < 2 * NN) {
        int k = tid >> 1, xy = tid & 1;
        sCoord[tid] = (k == 0) ? depot_xy[(size_t)b * 2 + xy]
                               : customer_xy[((size_t)b * NC + (k - 1)) * 2 + xy];
    }
    if (tid < NC) sDem[tid] = demand[(size_t)b * NC + tid];
    if (tid == 0) {
        sD = 1.f; sPrev = 0; sVis0 = 0ull; sVis1 = 0ull;
        sMaskDepot = 1; sCost = 0.0; sLL = 0.0; sTrig = 0; sOvf = 0;
        sPosX = depot_xy[(size_t)b * 2 + 0];
        sPosY = depot_xy[(size_t)b * 2 + 1];
    }
    // zero pad rows 101..103 of sV
    for (int i = tid; i < 3 * SVP; i += 512) sV[101 * SVP + i] = 0.f;

    // V and Kstep into LDS (fp32, float4 over columns)
    for (int idx = tid; idx < NN * 32; idx += 512) {
        int k  = idx >> 5;
        int e4 = (idx & 31) * 4;
        const float* er = emb + (size_t)k * E_;
        float4 aV = {0.f, 0.f, 0.f, 0.f};
        float4 aK = {0.f, 0.f, 0.f, 0.f};
        for (int g = 0; g < E_; ++g) {
            float eg = er[g];
            float4 wv = *(const float4*)(Wv      + (size_t)g * E_ + e4);
            float4 wq = *(const float4*)(Wq_step + (size_t)g * E_ + e4);
            aV.x += eg * wv.x; aV.y += eg * wv.y;
            aV.z += eg * wv.z; aV.w += eg * wv.w;
            aK.x += eg * wq.x; aK.y += eg * wq.y;
            aK.z += eg * wq.z; aK.w += eg * wq.w;
        }
        *(float4*)(sV  + (size_t)k * SVP + e4) = aV;
        *(float4*)(sKs + (size_t)k * E_  + e4) = aK;
    }

    // rA: K1h fragments; rK2: K2t fragments — BOTH per-head col range
    // [16h,16h+16) for this thread's two nodes (lane, lane+64).
    float rA[32], rK2[32];
#pragma unroll
    for (int j = 0; j < 32; ++j) { rA[j] = 0.f; rK2[j] = 0.f; }
    {
        const float* er0 = emb + (size_t)lane * E_;
        const float* er1 = emb + (size_t)((k1 < NN) ? k1 : lane) * E_;
        const float  e1s = (k1 < NN) ? 1.f : 0.f;
        const float* w1b = Wk1 + h * 16;
        const float* m2b = M32 + h * 16;
        for (int g = 0; g < E_; ++g) {
            float a0 = er0[g];
            float a1 = er1[g] * e1s;
            const float* w1 = w1b + (size_t)g * E_;
            const float* mm = m2b + (size_t)g * E_;
#pragma unroll
            for (int d = 0; d < 16; ++d) {
                rA[d]       += a0 * w1[d];
                rA[16 + d]  += a1 * w1[d];
                rK2[d]      += a0 * mm[d];
                rK2[16 + d] += a1 * mm[d];
            }
        }
    }
    __syncthreads();

    // ---------------- sequential decode loop ----------------
    for (int t = 0; t < T_; ++t) {
        // ---- BCD (fused, per-wave; no internal block barrier):
        //      scores -> exp -> glimpse dims of head h (in-register)
        //      -> per-head partial logits for own 2 nodes ----
        {
            int prev = sPrev;
            float Dv = sD;
            int d_ = h * 16 + (lane & 15);
            float q1v = (sQfix32[d_] + sKs[(size_t)prev * E_ + d_]
                         + Dv * sWqD32[d_]) * 0.25f;

            unsigned long long v0 = sVis0, v1 = sVis1;
            bool mk0, mk1;
            if (lane == 0) mk0 = (sMaskDepot != 0);
            else {
                int c = lane - 1;   // 0..62 -> always in sVis0
                mk0 = ((v0 >> c) & 1ull) || (sDem[c] > Dv);
            }
            if (k1 < NN) {
                int c = k1 - 1;     // 63..99
                bool vis = (c < 64) ? ((v0 >> c) & 1ull)
                                    : ((v1 >> (c - 64)) & 1ull);
                mk1 = vis || (sDem[c] > Dv);
            } else mk1 = true;

            float s0a = 0.f, s0b = 0.f, s1a = 0.f, s1b = 0.f;
#pragma unroll
            for (int d = 0; d < 8; ++d) {
                float qd = rdlane(q1v, d);
                s0a += rA[d] * qd;
                s1a += rA[16 + d] * qd;
            }
#pragma unroll
            for (int d = 8; d < 16; ++d) {
                float qd = rdlane(q1v, d);
                s0b += rA[d] * qd;
                s1b += rA[16 + d] * qd;
            }
            float s0 = s0a + s0b, s1 = s1a + s1b;
            bool ovf = (!mk0 && s0 > 80.f) || (!mk1 && s1 > 80.f);
            if (__any(ovf)) { if (lane == 0) sOvf = 1; }
            float w0 = mk0 ? 0.f : __expf(fminf(s0, 80.f));
            float w1 = mk1 ? 0.f : __expf(fminf(s1, 80.f));
            fSc[h * 104 + lane] = w0;
            if (k1 < 104) fSc[h * 104 + k1] = w1;

            __builtin_amdgcn_wave_barrier();  // pin write->read program order

            // glimpse dims of head h: chunk cq4 = lane>>4, 26 nodes each
            int cq4 = lane >> 4;
            const float* sc = fSc + h * 104 + cq4 * 26;
            const float* vv = sV + (size_t)(cq4 * 26) * SVP + d_;
            float p = 0.f, ssum = 0.f;
#pragma unroll
            for (int j = 0; j < 26; ++j) {
                float wgt = sc[j];              // pads (101..103) are 0
                p    += wgt * vv[(size_t)j * SVP];
                ssum += wgt;
            }
            p    += __shfl_xor(p, 16);
            ssum += __shfl_xor(ssum, 16);
            p    += __shfl_xor(p, 32);
            ssum += __shfl_xor(ssum, 32);
            // every lane now holds the full sums for dim d_ = h*16+(lane&15)
            float glval = p * (1.0f / ssum);

            // per-head partial logits for own 2 nodes (dims [16h,16h+16))
            float x0 = 0.f, x1 = 0.f;
#pragma unroll
            for (int d = 0; d < 16; ++d) {
                float gd = rdlane(glval, d);
                x0 += rK2[d] * gd;
                x1 += rK2[16 + d] * gd;
            }
            fPx8[h * E_ + lane] = x0;
            if (k1 < NN) fPx8[h * E_ + k1] = x1;
        }
        __syncthreads();

        // ---- E: sum 8 per-head partials, argmax + near-tie + commit ----
        if (tid < 64) {
            int kA = tid, kB = tid + 64;
            float xA = 0.f, xB = -3.0e38f;
#pragma unroll
            for (int hh = 0; hh < 8; ++hh) xA += fPx8[hh * E_ + kA];
            xA *= INVSQE;
            bool mk1;
            if (kA == 0) mk1 = (sMaskDepot != 0);
            else {
                int c = kA - 1;
                bool vis = (c < 64) ? ((sVis0 >> c) & 1ull) : ((sVis1 >> (c - 64)) & 1ull);
                mk1 = vis || (sDem[c] > sD);
            }
            bool mk2 = true;
            if (kB < NN) {
                float xs = 0.f;
#pragma unroll
                for (int hh = 0; hh < 8; ++hh) xs += fPx8[hh * E_ + kB];
                xB = xs * INVSQE;
                int c = kB - 1;
                bool vis = (c < 64) ? ((sVis0 >> c) & 1ull) : ((sVis1 >> (c - 64)) & 1ull);
                mk2 = vis || (sDem[c] > sD);
            }
            float a1v = mk1 ? -3.0e38f : xA;
            float a2v = mk2 ? -3.0e38f : xB;
            float m1; int mi;
            if (a2v > a1v) { m1 = a2v; mi = kB; }
            else           { m1 = a1v; mi = kA; }
            float ls = 0.f;
            if (!mk1)              ls += __expf(10.f * fast_tanh(xA));
            if (kB < NN && !mk2)   ls += __expf(10.f * fast_tanh(xB));
#pragma unroll
            for (int off = 32; off > 0; off >>= 1) {
                float om1 = __shfl_xor(m1, off);
                int   omi = __shfl_xor(mi, off);
                ls += __shfl_xor(ls, off);
                if (om1 > m1 || (om1 == m1 && omi < mi)) { m1 = om1; mi = omi; }
            }
            // near-tie ballot: exists another unmasked value > m1 - GAPTHR
            bool near = false;
            if (!mk1 && kA != mi && a1v > m1 - GAPTHR) near = true;
            if (!mk2 && kB != mi && a2v > m1 - GAPTHR) near = true;
            bool trigAny = __any(near);
            if (tid == 0) {
                bool trig = trigAny || (sOvf != 0) || !(m1 == m1);   // NaN-safe
                sOvf = 0;
                if (trig) {
                    sTrig = 1;
                } else {
                    float lsel = 10.f * fast_tanh(m1);
                    float logp = lsel - __logf(ls);
                    int nxt = mi;
                    sLL += (double)logp;
                    bool isdep = (nxt == 0);
                    if (isdep) {
                        sD = 1.0f;
                    } else {
                        int c = nxt - 1;
                        sD = sD - sDem[c];
                        if (c < 64) sVis0 |= (1ull << c);
                        else        sVis1 |= (1ull << (c - 64));
                    }
                    bool allv = (sVis0 == 0xFFFFFFFFFFFFFFFFull) &&
                                (sVis1 == 0x0000000FFFFFFFFFull);
                    sMaskDepot = (isdep && !allv) ? 1 : 0;
                    sPrev = nxt;
                    float cx = sCoord[2 * nxt], cy = sCoord[2 * nxt + 1];
                    double dx = (double)cx - (double)sPosX;
                    double dy = (double)cy - (double)sPosY;
                    sCost += sqrt(dx * dx + dy * dy + 1e-10);
                    sPosX = cx; sPosY = cy;
                }
            }
        }
        __syncthreads();

        // ---- Fallback: exact fp64 recompute of this step (rare) ----
        if (sTrig) {
            // F0: q1d
            if (tid < E_) {
                const float* ep = emb + (size_t)sPrev * E_;
                double ks = 0.0;
                for (int g = 0; g < E_; ++g)
                    ks += (double)ep[g] * (double)Wq_step[(size_t)g * E_ + tid];
                dQ1[tid] = (sQfix64[tid] + ks + (double)sD * sWqD64[tid]) * 0.25;
            }
            __syncthreads();
            // F1: u1[g][h]
            for (int idx = tid; idx < 1024; idx += 512) {
                int g = idx >> 3, hh = idx & 7;
                double u = 0.0;
#pragma unroll 4
                for (int d = 0; d < 16; ++d)
                    u += dQ1[hh * 16 + d] * (double)Wk1[(size_t)g * E_ + hh * 16 + d];
                dUZ[idx] = u;
            }
            __syncthreads();
            // F2: scores
            for (int idx = tid; idx < 1024; idx += 512) {
                int k = idx & 127, hh = idx >> 7;
                if (k < NN) {
                    bool mk;
                    if (k == 0) mk = (sMaskDepot != 0);
                    else {
                        int c = k - 1;
                        bool vis = (c < 64) ? ((sVis0 >> c) & 1ull) : ((sVis1 >> (c - 64)) & 1ull);
                        mk = vis || (sDem[c] > sD);
                    }
                    if (mk) dSc[hh * NN + k] = NEGV;
                    else {
                        const float* ek = emb + (size_t)k * E_;
                        double s = 0.0;
                        for (int g = 0; g < E_; ++g)
                            s += (double)ek[g] * dUZ[g * 8 + hh];
                        dSc[hh * NN + k] = s;
                    }
                }
            }
            __syncthreads();
            // F3: per-head softmax (wave hh), normalized weights in place
            {
                int hh = tid >> 6, ln = tid & 63;
                int kA = ln, kB = ln + 64;
                double v1 = dSc[hh * NN + kA];
                double v2 = (kB < NN) ? dSc[hh * NN + kB] : -1.0e300;
                double m = fmax(v1, v2);
#pragma unroll
                for (int off = 32; off > 0; off >>= 1)
                    m = fmax(m, __shfl_xor(m, off));
                double e1 = exp(v1 - m);
                double e2 = (kB < NN) ? exp(v2 - m) : 0.0;
                double s = e1 + e2;
#pragma unroll
                for (int off = 32; off > 0; off >>= 1)
                    s += __shfl_xor(s, off);
                double inv = 1.0 / s;
                dSc[hh * NN + kA] = e1 * inv;
                if (kB < NN) dSc[hh * NN + kB] = e2 * inv;
            }
            __syncthreads();
            // F4: z[g][h] = sum_k w[h][k] emb[k][g]
            for (int idx = tid; idx < 1024; idx += 512) {
                int g = idx >> 3, hh = idx & 7;
                double z = 0.0;
                for (int k = 0; k < NN; ++k)
                    z += dSc[hh * NN + k] * (double)emb[(size_t)k * E_ + g];
                dUZ[idx] = z;
            }
            __syncthreads();
            // F5: glimpse
            if (tid < E_) {
                int hh = tid >> 4;
                double g2 = 0.0;
                for (int g = 0; g < E_; ++g)
                    g2 += dUZ[g * 8 + hh] * (double)Wv[(size_t)g * E_ + tid];
                dGl[tid] = g2;
            }
            __syncthreads();
            // F6: vg = M64 @ glimpse
            if (tid < E_) {
                double v = 0.0;
                for (int e = 0; e < E_; ++e)
                    v += dGl[e] * M64[(size_t)tid * E_ + e];
                dVg[tid] = v;
            }
            __syncthreads();
            // F7: xd[k] (reuse dQ1)
            if (tid < NN) {
                const float* ek = emb + (size_t)tid * E_;
                double x = 0.0;
                for (int g = 0; g < E_; ++g)
                    x += (double)ek[g] * dVg[g];
                dQ1[tid] = x * INVSQED;
            }
            __syncthreads();
            // F8: fp64 argmax + LSE + commit
            if (tid < 64) {
                int kA = tid, kB = tid + 64;
                double x1 = dQ1[kA];
                bool mk1;
                if (kA == 0) mk1 = (sMaskDepot != 0);
                else {
                    int c = kA - 1;
                    bool vis = (c < 64) ? ((sVis0 >> c) & 1ull) : ((sVis1 >> (c - 64)) & 1ull);
                    mk1 = vis || (sDem[c] > sD);
                }
                double x2 = 0.0; bool mk2 = true;
                if (kB < NN) {
                    x2 = dQ1[kB];
                    int c = kB - 1;
                    bool vis = (c < 64) ? ((sVis0 >> c) & 1ull) : ((sVis1 >> (c - 64)) & 1ull);
                    mk2 = vis || (sDem[c] > sD);
                }
                double a1 = mk1 ? -1.0e300 : x1;
                double a2 = (kB < NN && !mk2) ? x2 : -1.0e300;
                double mv; int mi;
                if (a1 >= a2) { mv = a1; mi = kA; } else { mv = a2; mi = kB; }
#pragma unroll
                for (int off = 32; off > 0; off >>= 1) {
                    double ov = __shfl_xor(mv, off);
                    int    oi = __shfl_xor(mi, off);
                    if (ov > mv || (ov == mv && oi < mi)) { mv = ov; mi = oi; }
                }
                double lmax = 10.0 * tanh(mv);
                double l1 = mk1 ? NEGV : 10.0 * tanh(x1);
                double l2 = (kB < NN) ? (mk2 ? NEGV : 10.0 * tanh(x2)) : 0.0;
                double s = exp(l1 - lmax) + ((kB < NN) ? exp(l2 - lmax) : 0.0);
#pragma unroll
                for (int off = 32; off > 0; off >>= 1)
                    s += __shfl_xor(s, off);
                if (tid == 0) {
                    int nxt = mi;
                    sLL += -log(s);
                    bool isdep = (nxt == 0);
                    if (isdep) {
                        sD = 1.0f;
                    } else {
                        int c = nxt - 1;
                        sD = sD - sDem[c];
                        if (c < 64) sVis0 |= (1ull << c);
                        else        sVis1 |= (1ull << (c - 64));
                    }
                    bool allv = (sVis0 == 0xFFFFFFFFFFFFFFFFull) &&
                                (sVis1 == 0x0000000FFFFFFFFFull);
                    sMaskDepot = (isdep && !allv) ? 1 : 0;
                    sPrev = nxt;
                    float cx = sCoord[2 * nxt], cy = sCoord[2 * nxt + 1];
                    double dx = (double)cx - (double)sPosX;
                    double dy = (double)cy - (double)sPosY;
                    sCost += sqrt(dx * dx + dy * dy + 1e-10);
                    sPosX = cx; sPosY = cy;
                    sTrig = 0;
                }
            }
            __syncthreads();
        }
    }

    if (tid == 0) {
        double dx = (double)sCoord[0] - (double)sPosX;
        double dy = (double)sCoord[1] - (double)sPosY;
        out[b]      = (float)(sCost + sqrt(dx * dx + dy * dy + 1e-10));
        out[B_ + b] = (float)sLL;
    }
}

// ---------------------------------------------------------------------------
extern "C" void kernel_launch(void* const* d_in, const int* in_sizes, int n_in,
                              void* d_out, int out_size, void* d_ws, size_t ws_size,
                              hipStream_t stream) {
    const float* depot = (const float*)d_in[0];
    const float* cust  = (const float*)d_in[1];
    const float* dem   = (const float*)d_in[2];
    const float* nemb  = (const float*)d_in[3];
    const float* gemb  = (const float*)d_in[4];
    const float* Wk1   = (const float*)d_in[5];
    const float* Wv    = (const float*)d_in[6];
    const float* Wk2   = (const float*)d_in[7];
    const float* Wqf   = (const float*)d_in[8];
    const float* Wout  = (const float*)d_in[9];
    const float* Wqs   = (const float*)d_in[10];
    float*  out = (float*)d_out;
    double* M64 = (double*)d_ws;                       // 128 KB
    float*  M32 = (float*)((char*)d_ws + 131072);      // 64 KB

    k_weights<<<dim3(128), dim3(128), 0, stream>>>(Wk2, Wout, M64, M32);
    k_decode <<<dim3(B_),  dim3(512), 0, stream>>>(depot, cust, dem, nemb, gemb,
                                                   Wk1, Wv, Wqf, Wqs, M64, M32, out);
}

// Round 19
// 3011.859 us; speedup vs baseline: 2.0285x; 1.0391x over previous
//
#include <hip/hip_runtime.h>
#include <math.h>

// Problem constants (match reference)
#define B_   1024
#define NC   100
#define NN   101          // N = NC + 1
#define E_   128
#define T_   202          // 2*N
#define SVP  132          // sV row stride (padded, 16B-aligned rows)
#define NEGV   -1.0e9
#define GAPTHR 1.0e-3f    // decision guard band (round-14 proven)
#define INVSQE 0.08838834764831845f
#define INVSQED 0.08838834764831845

__device__ __forceinline__ float rdlane(float v, int l) {
    return __int_as_float(__builtin_amdgcn_readlane(__float_as_int(v), l));
}
// fast tanh via native exp (decisions use pre-tanh values; LL err << 3.5)
__device__ __forceinline__ float fast_tanh(float x) {
    float xc = fminf(fmaxf(x, -15.f), 15.f);
    float e  = __expf(2.f * xc);
    return (e - 1.f) / (e + 1.f);
}

// ---------------------------------------------------------------------------
// kernel 0: M = Wk2 @ Wout^T (128x128) into ws as fp64 (fallback) + fp32 (fast)
// ---------------------------------------------------------------------------
__global__ void k_weights(const float* __restrict__ Wk2,
                          const float* __restrict__ Wout,
                          double* __restrict__ M64,
                          float* __restrict__ M32) {
    int g = blockIdx.x;   // 0..127
    int e = threadIdx.x;  // 0..127
    const float* w2 = Wk2 + g * E_;
    const float* wo = Wout + e * E_;
    double acc = 0.0;
#pragma unroll 8
    for (int f = 0; f < E_; ++f) acc += (double)w2[f] * (double)wo[f];
    M64[g * E_ + e] = acc;
    M32[g * E_ + e] = (float)acc;
}

// ---------------------------------------------------------------------------
// Main decoder. 1 block / batch element, 512 threads (8 waves), (512,2).
// Round-18 structure (fused BCD, native transcendentals) + register state:
// phase E is executed REDUNDANTLY by all 8 waves (bit-identical), so the
// decode state (D, prev, visited, maskDepot, cost, LL, pos) lives in
// wave-uniform registers -> ONE __syncthreads per step. fPx8 + ovf flags are
// double-buffered by step parity (ahead-wave WAR safety); fSc is per-head
// private (wave_barrier ordered). fp64 near-tie fallback mirrors regs->LDS,
// runs the proven fallback body, reloads (uniform across waves).
// ---------------------------------------------------------------------------
__global__ __launch_bounds__(512, 2)
void k_decode(const float* __restrict__ depot_xy,
              const float* __restrict__ customer_xy,
              const float* __restrict__ demand,
              const float* __restrict__ node_emb,
              const float* __restrict__ graph_emb,
              const float* __restrict__ Wk1,
              const float* __restrict__ Wv,
              const float* __restrict__ Wq_fixed,
              const float* __restrict__ Wq_step,
              const double* __restrict__ M64,
              const float* __restrict__ M32,
              float* __restrict__ out)          // [2*B]: cost then ll
{
    __shared__ float  sKs[NN * E_];             // 51.7 KB Kstep rows fp32
    __shared__ __align__(16) float sV[104 * SVP]; // 54.9 KB V rows, padded
    __shared__ double sU[2224];                 // union scratch 17.8 KB
    __shared__ double sQfix64[E_];
    __shared__ double sWqD64[E_];
    __shared__ float  sQfix32[E_];
    __shared__ float  sWqD32[E_];
    __shared__ float  sCoord[2 * NN];
    __shared__ float  sDem[NC];
    // shared mirrors (fallback handoff only)
    __shared__ float  sD;
    __shared__ double sCost, sLL;
    __shared__ float  sPosX, sPosY;
    __shared__ int    sPrev, sMaskDepot, sTrig;
    __shared__ unsigned long long sVis0, sVis1;

    // fast fp32 views (overlay the fp64 fallback scratch)
    float* fSc  = (float*)sU;           // [8][104] exp-scores (per-head priv)
    float* fPxD = (float*)sU + 832;     // [2][8][128] dbl-buffered partials
    int*   sOvfA = (int*)((float*)sU + 2880);   // [2][8] per-head ovf flags
    // fallback fp64 views (not live at same time as fast views)
    double* dUZ = sU;                   // [128][8] u1 then z
    double* dSc = sU + 1024;            // [8][101] scores -> weights
    double* dQ1 = sU + 1832;            // [128] q1, later xd[101]
    double* dGl = sU + 1960;            // [128]
    double* dVg = sU + 2088;            // [128]

    const int b    = blockIdx.x;
    const int tid  = threadIdx.x;
    const int lane = tid & 63;
    const int h    = __builtin_amdgcn_readfirstlane(tid >> 6);   // head 0..7
    const int k1   = lane + 64;                                  // 2nd node

    const float* emb = node_emb + (size_t)b * NN * E_;

    // ---------------- prologue ----------------
    if (tid < E_) {
        const float* ge = graph_emb + (size_t)b * E_;
        double acc = 0.0;
        for (int g = 0; g < E_; ++g)
            acc += (double)ge[g] * (double)Wq_fixed[g * E_ + tid];
        sQfix64[tid] = acc;
        sQfix32[tid] = (float)acc;
        sWqD64[tid]  = (double)Wq_step[128 * E_ + tid];
        sWqD32[tid]  = Wq_step[128 * E_ + tid];
    }
    if (tid < 2 * NN) {
        int k = tid >> 1, xy = tid & 1;
        sCoord[tid] = (k == 0) ? depot_xy[(size_t)b * 2 + xy]
                               : customer_xy[((size_t)b * NC + (k - 1)) * 2 + xy];
    }
    if (tid < NC) sDem[tid] = demand[(size_t)b * NC + tid];
    if (tid == 0) sTrig = 0;
    // zero pad rows 101..103 of sV
    for (int i = tid; i < 3 * SVP; i += 512) sV[101 * SVP + i] = 0.f;

    // V and Kstep into LDS (fp32, float4 over columns)
    for (int idx = tid; idx < NN * 32; idx += 512) {
        int k  = idx >> 5;
        int e4 = (idx & 31) * 4;
        const float* er = emb + (size_t)k * E_;
        float4 aV = {0.f, 0.f, 0.f, 0.f};
        float4 aK = {0.f, 0.f, 0.f, 0.f};
        for (int g = 0; g < E_; ++g) {
            float eg = er[g];
            float4 wv = *(const float4*)(Wv      + (size_t)g * E_ + e4);
            float4 wq = *(const float4*)(Wq_step + (size_t)g * E_ + e4);
            aV.x += eg * wv.x; aV.y += eg * wv.y;
            aV.z += eg * wv.z; aV.w += eg * wv.w;
            aK.x += eg * wq.x; aK.y += eg * wq.y;
            aK.z += eg * wq.z; aK.w += eg * wq.w;
        }
        *(float4*)(sV  + (size_t)k * SVP + e4) = aV;
        *(float4*)(sKs + (size_t)k * E_  + e4) = aK;
    }

    // rA: K1h fragments; rK2: K2t fragments — per-head col range [16h,16h+16)
    // for this thread's two nodes (lane, lane+64).
    float rA[32], rK2[32];
#pragma unroll
    for (int j = 0; j < 32; ++j) { rA[j] = 0.f; rK2[j] = 0.f; }
    {
        const float* er0 = emb + (size_t)lane * E_;
        const float* er1 = emb + (size_t)((k1 < NN) ? k1 : lane) * E_;
        const float  e1s = (k1 < NN) ? 1.f : 0.f;
        const float* w1b = Wk1 + h * 16;
        const float* m2b = M32 + h * 16;
        for (int g = 0; g < E_; ++g) {
            float a0 = er0[g];
            float a1 = er1[g] * e1s;
            const float* w1 = w1b + (size_t)g * E_;
            const float* mm = m2b + (size_t)g * E_;
#pragma unroll
            for (int d = 0; d < 16; ++d) {
                rA[d]       += a0 * w1[d];
                rA[16 + d]  += a1 * w1[d];
                rK2[d]      += a0 * mm[d];
                rK2[16 + d] += a1 * mm[d];
            }
        }
    }

    // ---- register decode state (wave-uniform, identical across waves) ----
    float  rD = 1.0f;
    int    rPrev = 0, rMaskDep = 1;
    unsigned long long rV0 = 0ull, rV1 = 0ull;
    double rCost = 0.0, rLL = 0.0;
    float  rPx = depot_xy[(size_t)b * 2 + 0];
    float  rPy = depot_xy[(size_t)b * 2 + 1];
    __syncthreads();

    // ---------------- sequential decode loop ----------------
    for (int t = 0; t < T_; ++t) {
        const int bsel = t & 1;
        // ---- BCD (fused, per-wave): scores -> exp -> glimpse dims of head h
        //      (in-register) -> per-head partial logits for own 2 nodes ----
        {
            float Dv = rD;
            int d_ = h * 16 + (lane & 15);
            float q1v = (sQfix32[d_] + sKs[(size_t)rPrev * E_ + d_]
                         + Dv * sWqD32[d_]) * 0.25f;

            bool mk0, mk1;
            if (lane == 0) mk0 = (rMaskDep != 0);
            else {
                int c = lane - 1;   // 0..62 -> always in rV0
                mk0 = ((rV0 >> c) & 1ull) || (sDem[c] > Dv);
            }
            if (k1 < NN) {
                int c = k1 - 1;     // 63..99
                bool vis = (c < 64) ? ((rV0 >> c) & 1ull)
                                    : ((rV1 >> (c - 64)) & 1ull);
                mk1 = vis || (sDem[c] > Dv);
            } else mk1 = true;

            float s0a = 0.f, s0b = 0.f, s1a = 0.f, s1b = 0.f;
#pragma unroll
            for (int d = 0; d < 8; ++d) {
                float qd = rdlane(q1v, d);
                s0a += rA[d] * qd;
                s1a += rA[16 + d] * qd;
            }
#pragma unroll
            for (int d = 8; d < 16; ++d) {
                float qd = rdlane(q1v, d);
                s0b += rA[d] * qd;
                s1b += rA[16 + d] * qd;
            }
            float s0 = s0a + s0b, s1 = s1a + s1b;
            bool ovf = (!mk0 && s0 > 80.f) || (!mk1 && s1 > 80.f);
            int wOvf = __any(ovf) ? 1 : 0;
            if (lane == 0) sOvfA[bsel * 8 + h] = wOvf;
            float w0 = mk0 ? 0.f : __expf(fminf(s0, 80.f));
            float w1 = mk1 ? 0.f : __expf(fminf(s1, 80.f));
            fSc[h * 104 + lane] = w0;
            if (k1 < 104) fSc[h * 104 + k1] = w1;

            __builtin_amdgcn_wave_barrier();  // pin write->read program order

            // glimpse dims of head h: chunk cq4 = lane>>4, 26 nodes each
            int cq4 = lane >> 4;
            const float* sc = fSc + h * 104 + cq4 * 26;
            const float* vv = sV + (size_t)(cq4 * 26) * SVP + d_;
            float p = 0.f, ssum = 0.f;
#pragma unroll
            for (int j = 0; j < 26; ++j) {
                float wgt = sc[j];              // pads (101..103) are 0
                p    += wgt * vv[(size_t)j * SVP];
                ssum += wgt;
            }
            p    += __shfl_xor(p, 16);
            ssum += __shfl_xor(ssum, 16);
            p    += __shfl_xor(p, 32);
            ssum += __shfl_xor(ssum, 32);
            float glval = p * (1.0f / ssum);

            // per-head partial logits for own 2 nodes (dims [16h,16h+16))
            float x0 = 0.f, x1 = 0.f;
#pragma unroll
            for (int d = 0; d < 16; ++d) {
                float gd = rdlane(glval, d);
                x0 += rK2[d] * gd;
                x1 += rK2[16 + d] * gd;
            }
            float* px = fPxD + bsel * 1024 + h * E_;
            px[lane] = x0;
            if (k1 < NN) px[k1] = x1;
        }
        __syncthreads();   // the ONLY per-step block barrier

        // ---- E (ALL waves, redundant & bit-identical): sum 8 partials,
        //      argmax + near-tie + register-state commit ----
        {
            int kA = lane, kB = k1;
            const float* px = fPxD + bsel * 1024;
            float xA = 0.f;
#pragma unroll
            for (int hh = 0; hh < 8; ++hh) xA += px[hh * E_ + kA];
            xA *= INVSQE;
            bool mk1;
            if (kA == 0) mk1 = (rMaskDep != 0);
            else {
                int c = kA - 1;
                bool vis = (c < 64) ? ((rV0 >> c) & 1ull) : ((rV1 >> (c - 64)) & 1ull);
                mk1 = vis || (sDem[c] > rD);
            }
            float xB = -3.0e38f; bool mk2 = true;
            if (kB < NN) {
                float xs = 0.f;
#pragma unroll
                for (int hh = 0; hh < 8; ++hh) xs += px[hh * E_ + kB];
                xB = xs * INVSQE;
                int c = kB - 1;
                bool vis = (c < 64) ? ((rV0 >> c) & 1ull) : ((rV1 >> (c - 64)) & 1ull);
                mk2 = vis || (sDem[c] > rD);
            }
            int oa = 0;
#pragma unroll
            for (int hh = 0; hh < 8; ++hh) oa |= sOvfA[bsel * 8 + hh];

            float a1v = mk1 ? -3.0e38f : xA;
            float a2v = mk2 ? -3.0e38f : xB;
            float m1; int mi;
            if (a2v > a1v) { m1 = a2v; mi = kB; }
            else           { m1 = a1v; mi = kA; }
            float ls = 0.f;
            if (!mk1)              ls += __expf(10.f * fast_tanh(xA));
            if (kB < NN && !mk2)   ls += __expf(10.f * fast_tanh(xB));
#pragma unroll
            for (int off = 32; off > 0; off >>= 1) {
                float om1 = __shfl_xor(m1, off);
                int   omi = __shfl_xor(mi, off);
                ls += __shfl_xor(ls, off);
                if (om1 > m1 || (om1 == m1 && omi < mi)) { m1 = om1; mi = omi; }
            }
            bool near = false;
            if (!mk1 && kA != mi && a1v > m1 - GAPTHR) near = true;
            if (!mk2 && kB != mi && a2v > m1 - GAPTHR) near = true;
            bool trigAny = __any(near);
            bool trig = trigAny || (oa != 0) || !(m1 == m1);   // NaN-safe

            if (!trig) {
                // uniform register-state commit (all lanes, all waves)
                int nxt = mi;
                float lsel = 10.f * fast_tanh(m1);
                float logp = lsel - __logf(ls);
                rLL += (double)logp;
                bool isdep = (nxt == 0);
                if (isdep) {
                    rD = 1.0f;
                } else {
                    int c = nxt - 1;
                    rD = rD - sDem[c];
                    if (c < 64) rV0 |= (1ull << c);
                    else        rV1 |= (1ull << (c - 64));
                }
                bool allv = (rV0 == 0xFFFFFFFFFFFFFFFFull) &&
                            (rV1 == 0x0000000FFFFFFFFFull);
                rMaskDep = (isdep && !allv) ? 1 : 0;
                rPrev = nxt;
                float cx = sCoord[2 * nxt], cy = sCoord[2 * nxt + 1];
                double dx = (double)cx - (double)rPx;
                double dy = (double)cy - (double)rPy;
                rCost += sqrt(dx * dx + dy * dy + 1e-10);
                rPx = cx; rPy = cy;
            } else {
                // ---- fallback: mirror regs -> LDS, exact fp64 step, reload --
                if (tid == 0) {
                    sD = rD; sPrev = rPrev; sMaskDepot = rMaskDep;
                    sVis0 = rV0; sVis1 = rV1;
                    sCost = rCost; sLL = rLL; sPosX = rPx; sPosY = rPy;
                    sTrig = 1;
                }
                __syncthreads();
                // F0: q1d
                if (tid < E_) {
                    const float* ep = emb + (size_t)sPrev * E_;
                    double ks = 0.0;
                    for (int g = 0; g < E_; ++g)
                        ks += (double)ep[g] * (double)Wq_step[(size_t)g * E_ + tid];
                    dQ1[tid] = (sQfix64[tid] + ks + (double)sD * sWqD64[tid]) * 0.25;
                }
                __syncthreads();
                for (int idx = tid; idx < 1024; idx += 512) {
                    int g = idx >> 3, hh = idx & 7;
                    double u = 0.0;
#pragma unroll 4
                    for (int d = 0; d < 16; ++d)
                        u += dQ1[hh * 16 + d] * (double)Wk1[(size_t)g * E_ + hh * 16 + d];
                    dUZ[idx] = u;
                }
                __syncthreads();
                for (int idx = tid; idx < 1024; idx += 512) {
                    int k = idx & 127, hh = idx >> 7;
                    if (k < NN) {
                        bool mk;
                        if (k == 0) mk = (sMaskDepot != 0);
                        else {
                            int c = k - 1;
                            bool vis = (c < 64) ? ((sVis0 >> c) & 1ull) : ((sVis1 >> (c - 64)) & 1ull);
                            mk = vis || (sDem[c] > sD);
                        }
                        if (mk) dSc[hh * NN + k] = NEGV;
                        else {
                            const float* ek = emb + (size_t)k * E_;
                            double s = 0.0;
                            for (int g = 0; g < E_; ++g)
                                s += (double)ek[g] * dUZ[g * 8 + hh];
                            dSc[hh * NN + k] = s;
                        }
                    }
                }
                __syncthreads();
                {
                    int hh = tid >> 6, ln = tid & 63;
                    int kA2 = ln, kB2 = ln + 64;
                    double v1 = dSc[hh * NN + kA2];
                    double v2 = (kB2 < NN) ? dSc[hh * NN + kB2] : -1.0e300;
                    double m = fmax(v1, v2);
#pragma unroll
                    for (int off = 32; off > 0; off >>= 1)
                        m = fmax(m, __shfl_xor(m, off));
                    double e1 = exp(v1 - m);
                    double e2 = (kB2 < NN) ? exp(v2 - m) : 0.0;
                    double s = e1 + e2;
#pragma unroll
                    for (int off = 32; off > 0; off >>= 1)
                        s += __shfl_xor(s, off);
                    double inv = 1.0 / s;
                    dSc[hh * NN + kA2] = e1 * inv;
                    if (kB2 < NN) dSc[hh * NN + kB2] = e2 * inv;
                }
                __syncthreads();
                for (int idx = tid; idx < 1024; idx += 512) {
                    int g = idx >> 3, hh = idx & 7;
                    double z = 0.0;
                    for (int k = 0; k < NN; ++k)
                        z += dSc[hh * NN + k] * (double)emb[(size_t)k * E_ + g];
                    dUZ[idx] = z;
                }
                __syncthreads();
                if (tid < E_) {
                    int hh = tid >> 4;
                    double g2 = 0.0;
                    for (int g = 0; g < E_; ++g)
                        g2 += dUZ[g * 8 + hh] * (double)Wv[(size_t)g * E_ + tid];
                    dGl[tid] = g2;
                }
                __syncthreads();
                if (tid < E_) {
                    double v = 0.0;
                    for (int e = 0; e < E_; ++e)
                        v += dGl[e] * M64[(size_t)tid * E_ + e];
                    dVg[tid] = v;
                }
                __syncthreads();
                if (tid < NN) {
                    const float* ek = emb + (size_t)tid * E_;
                    double x = 0.0;
                    for (int g = 0; g < E_; ++g)
                        x += (double)ek[g] * dVg[g];
                    dQ1[tid] = x * INVSQED;
                }
                __syncthreads();
                if (tid < 64) {
                    int kA2 = tid, kB2 = tid + 64;
                    double x1 = dQ1[kA2];
                    bool fk1;
                    if (kA2 == 0) fk1 = (sMaskDepot != 0);
                    else {
                        int c = kA2 - 1;
                        bool vis = (c < 64) ? ((sVis0 >> c) & 1ull) : ((sVis1 >> (c - 64)) & 1ull);
                        fk1 = vis || (sDem[c] > sD);
                    }
                    double x2 = 0.0; bool fk2 = true;
                    if (kB2 < NN) {
                        x2 = dQ1[kB2];
                        int c = kB2 - 1;
                        bool vis = (c < 64) ? ((sVis0 >> c) & 1ull) : ((sVis1 >> (c - 64)) & 1ull);
                        fk2 = vis || (sDem[c] > sD);
                    }
                    double a1 = fk1 ? -1.0e300 : x1;
                    double a2 = (kB2 < NN && !fk2) ? x2 : -1.0e300;
                    double mv; int fmi;
                    if (a1 >= a2) { mv = a1; fmi = kA2; } else { mv = a2; fmi = kB2; }
#pragma unroll
                    for (int off = 32; off > 0; off >>= 1) {
                        double ov = __shfl_xor(mv, off);
                        int    oi = __shfl_xor(fmi, off);
                        if (ov > mv || (ov == mv && oi < fmi)) { mv = ov; fmi = oi; }
                    }
                    double lmax = 10.0 * tanh(mv);
                    double l1 = fk1 ? NEGV : 10.0 * tanh(x1);
                    double l2 = (kB2 < NN) ? (fk2 ? NEGV : 10.0 * tanh(x2)) : 0.0;
                    double s = exp(l1 - lmax) + ((kB2 < NN) ? exp(l2 - lmax) : 0.0);
#pragma unroll
                    for (int off = 32; off > 0; off >>= 1)
                        s += __shfl_xor(s, off);
                    if (tid == 0) {
                        int nxt = fmi;
                        sLL += -log(s);
                        bool isdep = (nxt == 0);
                        if (isdep) {
                            sD = 1.0f;
                        } else {
                            int c = nxt - 1;
                            sD = sD - sDem[c];
                            if (c < 64) sVis0 |= (1ull << c);
                            else        sVis1 |= (1ull << (c - 64));
                        }
                        bool allv = (sVis0 == 0xFFFFFFFFFFFFFFFFull) &&
                                    (sVis1 == 0x0000000FFFFFFFFFull);
                        sMaskDepot = (isdep && !allv) ? 1 : 0;
                        sPrev = nxt;
                        float cx = sCoord[2 * nxt], cy = sCoord[2 * nxt + 1];
                        double dx = (double)cx - (double)sPosX;
                        double dy = (double)cy - (double)sPosY;
                        sCost += sqrt(dx * dx + dy * dy + 1e-10);
                        sPosX = cx; sPosY = cy;
                        sTrig = 0;
                    }
                }
                __syncthreads();
                // reload register state (all waves)
                rD = sD; rPrev = sPrev; rMaskDep = sMaskDepot;
                rV0 = sVis0; rV1 = sVis1;
                rCost = sCost; rLL = sLL; rPx = sPosX; rPy = sPosY;
            }
        }
    }

    if (tid == 0) {
        double dx = (double)sCoord[0] - (double)rPx;
        double dy = (double)sCoord[1] - (double)rPy;
        out[b]      = (float)(rCost + sqrt(dx * dx + dy * dy + 1e-10));
        out[B_ + b] = (float)rLL;
    }
}

// ---------------------------------------------------------------------------
extern "C" void kernel_launch(void* const* d_in, const int* in_sizes, int n_in,
                              void* d_out, int out_size, void* d_ws, size_t ws_size,
                              hipStream_t stream) {
    const float* depot = (const float*)d_in[0];
    const float* cust  = (const float*)d_in[1];
    const float* dem   = (const float*)d_in[2];
    const float* nemb  = (const float*)d_in[3];
    const float* gemb  = (const float*)d_in[4];
    const float* Wk1   = (const float*)d_in[5];
    const float* Wv    = (const float*)d_in[6];
    const float* Wk2   = (const float*)d_in[7];
    const float* Wqf   = (const float*)d_in[8];
    const float* Wout  = (const float*)d_in[9];
    const float* Wqs   = (const float*)d_in[10];
    float*  out = (float*)d_out;
    double* M64 = (double*)d_ws;                       // 128 KB
    float*  M32 = (float*)((char*)d_ws + 131072);      // 64 KB

    k_weights<<<dim3(128), dim3(128), 0, stream>>>(Wk2, Wout, M64, M32);
    k_decode <<<dim3(B_),  dim3(512), 0, stream>>>(depot, cust, dem, nemb, gemb,
                                                   Wk1, Wv, Wqf, Wqs, M64, M32, out);
}